// Round 3
// baseline (128.458 us; speedup 1.0000x reference)
//
#include <hip/hip_runtime.h>

#define A_ 8732
#define B_ 32
#define N_ 100
#define NBLK 35  // ceil(A_/256)
#define EPSF 1e-6f

// DPP max helper: x = max(x, dpp_shift(x)). Runs on VALU pipe (no DS ops).
// bound_ctrl=false + old=x -> out-of-row source lanes contribute x (identity).
template <int CTRL>
__device__ __forceinline__ float dpp_max(float x) {
  int xi = __float_as_int(x);
  int s = __builtin_amdgcn_update_dpp(xi, xi, CTRL, 0xf, 0xf, false);
  return fmaxf(x, __int_as_float(s));
}
#define ROW_SHR(n) (0x110 + (n))
#define ROW_BCAST15 0x142
#define ROW_BCAST31 0x143

// ws layout:
//   partial[B_*N_*NBLK] u64  -- per-(b,n) per-block best keys
//   (map lives in ws after partial)
// All used ws regions are fully overwritten every launch (no init needed).

// ---------------------------------------------------------------------------
// K1: per (b, a) — per-anchor max/argmax over n (strict '>' ascending ==
// numpy first-occurrence), PLUS per-n reduction over this wave's 64 anchors
// done with DPP (VALU-only) instead of DS shuffles.
// Key = (iou_bits << 32) | (0xFFFFFFFF - a): IoU >= +0 and never -0 (clipped
// w,h are fmax(x,+0) so never -0; inter = w*h >= +0), so float bits are
// monotone unsigned; inverted index gives first-occurrence tie-breaking.
// GT boxes read via wave-uniform global loads (compiler -> s_load_dwordx4).
// ---------------------------------------------------------------------------
__global__ __launch_bounds__(256) void k_main(
    const float* __restrict__ gt, const float* __restrict__ anchors,
    float* __restrict__ bg_iou, int* __restrict__ bg_idx,
    unsigned long long* __restrict__ partial, int* __restrict__ map) {
  int b = blockIdx.y;
  int bx = blockIdx.x;
  int tid = threadIdx.x;
  int a = bx * 256 + tid;
  bool valid = a < A_;
  int aa = valid ? a : (A_ - 1);

  __shared__ unsigned long long s_part[4 * N_];

  const float4* g4 = (const float4*)(gt + (size_t)b * N_ * 4);  // uniform

  float4 an = ((const float4*)anchors)[aa];
  float ax0 = an.x - an.z * 0.5f, ay0 = an.y - an.w * 0.5f;
  float ax1 = an.x + an.z * 0.5f, ay1 = an.y + an.w * 0.5f;
  float area_a = (ax1 - ax0) * (ay1 - ay0);

  int wid = tid >> 6;
  int lane = tid & 63;
  int wave_a0 = bx * 256 + wid * 64;  // anchor of lane 0 of this wave

  float best = -1.0f;
  int bi = 0;
#pragma unroll 2
  for (int n = 0; n < N_; n++) {
    float4 gb = g4[n];  // wave-uniform -> scalar load
    float bx0 = gb.x, by0 = gb.y, bx1 = gb.z, by1 = gb.w;
    float lx = fmaxf(ax0, bx0), ly = fmaxf(ay0, by0);
    float rx = fminf(ax1, bx1), ry = fminf(ay1, by1);
    float w = fmaxf(rx - lx, 0.0f), h = fmaxf(ry - ly, 0.0f);
    float inter = w * h;
    float area_b = (bx1 - bx0) * (by1 - by0);
    float uni = area_a + area_b - inter;
    float iou = inter / fmaxf(uni, EPSF);

    // per-anchor running argmax (first occurrence)
    if (iou > best) { best = iou; bi = n; }

    // per-n wave max over the 64 anchors of this wave — DPP reduce to lane 63
    float r = valid ? iou : 0.0f;
    float m = r;
    m = dpp_max<ROW_SHR(1)>(m);
    m = dpp_max<ROW_SHR(2)>(m);
    m = dpp_max<ROW_SHR(4)>(m);
    m = dpp_max<ROW_SHR(8)>(m);   // lane 15 of each row = row max
    m = dpp_max<ROW_BCAST15>(m);  // lane 31 = rows 0-1 max, lane 63 = rows 2-3
    m = dpp_max<ROW_BCAST31>(m);  // lane 63 = full wave max
    int wm_i = __builtin_amdgcn_readlane(__float_as_int(m), 63);  // uniform
    float wmax = __int_as_float(wm_i);
    unsigned long long winners = __ballot(r == wmax);
    int wl = __ffsll(winners) - 1;  // lowest lane == smallest anchor idx
    unsigned aw = (unsigned)(wave_a0 + wl);
    unsigned inva = (aw < A_) ? (0xFFFFFFFFu - aw) : 0u;
    if (lane == 0) {
      s_part[wid * N_ + n] =
          (((unsigned long long)(unsigned)wm_i) << 32) |
          (unsigned long long)inva;
    }
  }

  if (valid) {
    size_t idx = (size_t)b * A_ + a;
    bg_iou[idx] = best;
    bg_idx[idx] = bi;
    map[idx] = -1;  // init override map for K2's atomicMax
  }

  __syncthreads();
  for (int n = tid; n < N_; n += 256) {
    unsigned long long k = s_part[n];
    unsigned long long t;
    t = s_part[N_ + n];     if (t > k) k = t;
    t = s_part[2 * N_ + n]; if (t > k) k = t;
    t = s_part[3 * N_ + n]; if (t > k) k = t;
    partial[((size_t)b * N_ + n) * NBLK + bx] = k;
  }
}

// ---------------------------------------------------------------------------
// K2: per (b, n) — reduce 35 block partials -> winning anchor; last-write-
// wins scatter expressed as atomicMax over n (largest n == last write, exact
// index_put semantics). Also computes any_valid per batch.
// ---------------------------------------------------------------------------
__global__ __launch_bounds__(256) void k_combine(
    const unsigned long long* __restrict__ partial,
    const unsigned char* __restrict__ mask,
    int* __restrict__ map, int* __restrict__ any_valid) {
  int bn = blockIdx.x * 256 + threadIdx.x;
  if (bn >= B_ * N_) return;
  const unsigned long long* p = partial + (size_t)bn * NBLK;
  unsigned long long k = p[0];
  for (int i = 1; i < NBLK; i++) {
    unsigned long long t = p[i];
    if (t > k) k = t;
  }
  int b = bn / N_;
  int n = bn - b * N_;
  unsigned a_win = 0xFFFFFFFFu - (unsigned)(k & 0xFFFFFFFFull);
  atomicMax(&map[(size_t)b * A_ + a_win], n);
  if (n == 0) {
    int any = 0;
    for (int j = 0; j < N_; j++) any |= mask[b * N_ + j];
    any_valid[b] = any ? 1 : 0;
  }
}

// ---------------------------------------------------------------------------
// K3: per (b, a) — apply override map, gather matched GT, encode, write.
// bg_iou / bg_idx alias the label/mask regions of d_out; each thread reads
// its slots before overwriting them (no __restrict__ on aliased pointers).
// Math kept bit-identical to the passing version.
// ---------------------------------------------------------------------------
__global__ __launch_bounds__(256) void k_finalize(
    const float* __restrict__ gt, const int* __restrict__ labels,
    const float* __restrict__ anchors, const int* __restrict__ any_valid,
    const int* __restrict__ map, const float* bg_iou, const int* bg_idx,
    float* out) {
  const long long BA = (long long)B_ * A_;
  long long idx = (long long)blockIdx.x * 256 + threadIdx.x;
  if (idx >= BA) return;
  int b = (int)(idx / A_);
  int a = (int)(idx - (long long)b * A_);

  float iou = bg_iou[idx];
  int gi = bg_idx[idx];
  int ov = map[idx];
  bool pos;
  if (ov >= 0) {
    gi = ov;
    pos = true;  // scattered best_gt_iou = 2.0 > 0.5
  } else {
    pos = iou > 0.5f;
  }

  float4 an = ((const float4*)anchors)[a];
  const float* g = gt + (size_t)(b * N_ + gi) * 4;
  float gx = g[0], gy = g[1], gw = g[2], gh = g[3];

  float ex = (gx - an.x) / an.z;
  float ey = (gy - an.y) / an.w;
  float ew = logf((gw + EPSF) / (an.z + EPSF));
  float eh = logf((gh + EPSF) / (an.w + EPSF));
  int lab = pos ? labels[b * N_ + gi] : 0;

  if (!any_valid[b]) { ex = 0.0f; ey = 0.0f; ew = 0.0f; eh = 0.0f; lab = 0; }

  ((float4*)out)[idx] = make_float4(ex, ey, ew, eh);  // encoded [B,A,4]
  out[4 * BA + idx] = (float)lab;                     // labels  [B,A]
  out[5 * BA + idx] = pos ? 1.0f : 0.0f;              // pos_mask[B,A]
}

extern "C" void kernel_launch(void* const* d_in, const int* in_sizes, int n_in,
                              void* d_out, int out_size, void* d_ws,
                              size_t ws_size, hipStream_t stream) {
  const float* gt = (const float*)d_in[0];
  const int* labels = (const int*)d_in[1];
  const unsigned char* mask = (const unsigned char*)d_in[2];
  const float* anchors = (const float*)d_in[3];
  float* out = (float*)d_out;

  const size_t BA = (size_t)B_ * A_;
  // Scratch-in-output: label region holds best_gt_iou, mask region holds
  // best_gt_idx until K3 overwrites them (read-before-write per thread).
  float* bg_iou = out + 4 * BA;
  int* bg_idx = (int*)(out + 5 * BA);

  // ws scratch
  unsigned long long* partial = (unsigned long long*)d_ws;  // B*N*NBLK u64
  int* map = (int*)(partial + (size_t)B_ * N_ * NBLK);      // B*A int
  int* any_valid = map + BA;                                // B int

  dim3 g1(NBLK, B_);
  k_main<<<g1, 256, 0, stream>>>(gt, anchors, bg_iou, bg_idx, partial, map);
  k_combine<<<(B_ * N_ + 255) / 256, 256, 0, stream>>>(partial, mask, map,
                                                       any_valid);
  k_finalize<<<(int)((BA + 255) / 256), 256, 0, stream>>>(
      gt, labels, anchors, any_valid, map, bg_iou, bg_idx, out);
}

// Round 4
// 113.273 us; speedup vs baseline: 1.1341x; 1.1341x over previous
//
#include <hip/hip_runtime.h>

#define A_ 8732
#define B_ 32
#define N_ 100
#define ABLK 35               // ceil(A_/256)
#define NSPLIT 2
#define HALF_N 50
#define GRID_A (ABLK * B_ * NSPLIT)  // 2240 per-anchor blocks
#define GRID_B (B_ * N_)             // 3200 per-GT blocks
#define EPSF 1e-6f

// ws layout (all regions fully overwritten every launch, no init needed):
//   partA[B_*A_*2] u64 -- per-(b,a) best (iou,n) key, one per n-half (~4.5 MB)
//   win[B_*N_] int     -- winning anchor per (b,n)

// ---------------------------------------------------------------------------
// K1 merged scan. Branch on blockIdx (block-uniform, no divergence inside a
// block). IoU expression is textually identical in both branches -> bit-exact
// identical values for the same (b,a,n). IoU >= +0 and never -0 (clipped w,h
// come from fmaxf(x,0) so never -0; inter = w*h >= +0), so float bits are
// monotone unsigned in the packed keys.
//
// Branch A: thread = (b,a), serial argmax over one half of the GTs.
//   key = (iou_bits<<32) | (99-n): max -> highest iou, tie -> smallest n
//   (numpy first-occurrence). Pure VALU loop, no cross-lane ops.
// Branch B: block = (b,n), threads stride anchors (35 iters), single LDS tree
//   reduce at the end. key = (iou_bits<<32) | (0xFFFFFFFF-a): tie -> smallest
//   anchor index (numpy first-occurrence).
// ---------------------------------------------------------------------------
__global__ __launch_bounds__(256) void k_scan(
    const float* __restrict__ gt, const float* __restrict__ anchors,
    unsigned long long* __restrict__ partA, int* __restrict__ win) {
  int tid = threadIdx.x;
  int bid = blockIdx.x;
  __shared__ unsigned long long sred[256];

  if (bid < GRID_A) {
    // ---- per-anchor argmax over n in [half*50, half*50+50) ----
    int bx = bid % ABLK;
    int t = bid / ABLK;
    int b = t >> 1;
    int half = t & 1;
    int a = bx * 256 + tid;
    bool valid = a < A_;
    int aa = valid ? a : (A_ - 1);

    const float4* g4 = (const float4*)(gt + (size_t)b * N_ * 4);  // uniform
    float4 an = ((const float4*)anchors)[aa];
    float ax0 = an.x - an.z * 0.5f, ay0 = an.y - an.w * 0.5f;
    float ax1 = an.x + an.z * 0.5f, ay1 = an.y + an.w * 0.5f;
    float area_a = (ax1 - ax0) * (ay1 - ay0);

    unsigned long long bestk = 0ull;
    int n0 = half * HALF_N;
#pragma unroll 5
    for (int i = 0; i < HALF_N; i++) {
      int n = n0 + i;
      float4 gb = g4[n];  // wave-uniform -> scalar load
      float bx0 = gb.x, by0 = gb.y, bx1 = gb.z, by1 = gb.w;
      float lx = fmaxf(ax0, bx0), ly = fmaxf(ay0, by0);
      float rx = fminf(ax1, bx1), ry = fminf(ay1, by1);
      float w = fmaxf(rx - lx, 0.0f), h = fmaxf(ry - ly, 0.0f);
      float inter = w * h;
      float area_b = (bx1 - bx0) * (by1 - by0);
      float uni = area_a + area_b - inter;
      float iou = inter / fmaxf(uni, EPSF);
      unsigned long long key =
          (((unsigned long long)__float_as_uint(iou)) << 32) |
          (unsigned long long)(unsigned)(N_ - 1 - n);
      if (key > bestk) bestk = key;
    }
    if (valid) partA[((size_t)b * A_ + a) * 2 + half] = bestk;
  } else {
    // ---- per-GT argmax over anchors ----
    int bn = bid - GRID_A;
    int b = bn / N_, n = bn - b * N_;
    const float* g = gt + (size_t)(b * N_ + n) * 4;
    float bx0 = g[0], by0 = g[1], bx1 = g[2], by1 = g[3];
    float area_b = (bx1 - bx0) * (by1 - by0);

    unsigned long long bestkey = 0ull;
    for (int a = tid; a < A_; a += 256) {
      float4 an = ((const float4*)anchors)[a];
      float ax0 = an.x - an.z * 0.5f, ay0 = an.y - an.w * 0.5f;
      float ax1 = an.x + an.z * 0.5f, ay1 = an.y + an.w * 0.5f;
      float lx = fmaxf(ax0, bx0), ly = fmaxf(ay0, by0);
      float rx = fminf(ax1, bx1), ry = fminf(ay1, by1);
      float w = fmaxf(rx - lx, 0.0f), h = fmaxf(ry - ly, 0.0f);
      float inter = w * h;
      float area_a = (ax1 - ax0) * (ay1 - ay0);
      float uni = area_a + area_b - inter;
      float iou = inter / fmaxf(uni, EPSF);
      unsigned long long key =
          (((unsigned long long)__float_as_uint(iou)) << 32) |
          (unsigned long long)(0xFFFFFFFFu - (unsigned)a);
      if (key > bestkey) bestkey = key;
    }
    sred[tid] = bestkey;
    __syncthreads();
    for (int s = 128; s > 0; s >>= 1) {
      if (tid < s) {
        unsigned long long o = sred[tid + s];
        if (o > sred[tid]) sred[tid] = o;
      }
      __syncthreads();
    }
    if (tid == 0)
      win[bn] = (int)(0xFFFFFFFFu - (unsigned)(sred[0] & 0xFFFFFFFFull));
  }
}

// ---------------------------------------------------------------------------
// K2: per (b, 256-anchor tile) — build LDS override table from win[] via
// LDS atomicMax (largest n == last write, exact index_put semantics), merge
// the two per-anchor key halves, encode, write all outputs.
// ---------------------------------------------------------------------------
__global__ __launch_bounds__(256) void k_finalize(
    const float* __restrict__ gt, const int* __restrict__ labels,
    const float* __restrict__ anchors, const unsigned char* __restrict__ mask,
    const unsigned long long* __restrict__ partA, const int* __restrict__ win,
    float* __restrict__ out) {
  int b = blockIdx.y;
  int a0 = blockIdx.x * 256;
  int tid = threadIdx.x;
  int a = a0 + tid;

  __shared__ int s_ov[256];
  __shared__ int s_any;
  if (tid == 0) s_any = 0;
  s_ov[tid] = -1;
  __syncthreads();
  if (tid < N_) {
    int aw = win[b * N_ + tid];
    if (aw >= a0 && aw < a0 + 256) atomicMax(&s_ov[aw - a0], tid);
  }
  if (tid < 25) {
    // mask row b spans >=100 bytes whether bool landed as u8 or i32; all
    // interpretations give nonzero words iff any True (data here: all True).
    unsigned v = ((const unsigned*)mask)[b * 25 + tid];
    if (v) atomicOr(&s_any, 1);
  }
  __syncthreads();
  if (a >= A_) return;

  size_t idx = (size_t)b * A_ + a;
  unsigned long long k0 = partA[idx * 2];
  unsigned long long k1 = partA[idx * 2 + 1];
  unsigned long long k = (k0 > k1) ? k0 : k1;
  float iou = __uint_as_float((unsigned)(k >> 32));
  int gi = (N_ - 1) - (int)(k & 0xFFFFFFFFull);

  int ov = s_ov[tid];
  bool pos;
  if (ov >= 0) {
    gi = ov;
    pos = true;  // scattered best_gt_iou = 2.0 > 0.5
  } else {
    pos = iou > 0.5f;
  }

  float4 an = ((const float4*)anchors)[a];
  const float* g = gt + (size_t)(b * N_ + gi) * 4;
  float gx = g[0], gy = g[1], gw = g[2], gh = g[3];

  float ex = (gx - an.x) / an.z;
  float ey = (gy - an.y) / an.w;
  float ew = logf((gw + EPSF) / (an.z + EPSF));
  float eh = logf((gh + EPSF) / (an.w + EPSF));
  int lab = pos ? labels[b * N_ + gi] : 0;

  if (!s_any) { ex = 0.0f; ey = 0.0f; ew = 0.0f; eh = 0.0f; lab = 0; }

  const long long BA = (long long)B_ * A_;
  ((float4*)out)[idx] = make_float4(ex, ey, ew, eh);  // encoded [B,A,4]
  out[4 * BA + idx] = (float)lab;                     // labels  [B,A]
  out[5 * BA + idx] = pos ? 1.0f : 0.0f;              // pos_mask[B,A]
}

extern "C" void kernel_launch(void* const* d_in, const int* in_sizes, int n_in,
                              void* d_out, int out_size, void* d_ws,
                              size_t ws_size, hipStream_t stream) {
  const float* gt = (const float*)d_in[0];
  const int* labels = (const int*)d_in[1];
  const unsigned char* mask = (const unsigned char*)d_in[2];
  const float* anchors = (const float*)d_in[3];
  float* out = (float*)d_out;

  unsigned long long* partA = (unsigned long long*)d_ws;  // B*A*2 u64
  int* win = (int*)(partA + (size_t)B_ * A_ * 2);         // B*N int

  k_scan<<<GRID_A + GRID_B, 256, 0, stream>>>(gt, anchors, partA, win);
  k_finalize<<<dim3(ABLK, B_), 256, 0, stream>>>(gt, labels, anchors, mask,
                                                 partA, win, out);
}

// Round 6
// 104.093 us; speedup vs baseline: 1.2341x; 1.0882x over previous
//
#include <hip/hip_runtime.h>

#define A_ 8732
#define B_ 32
#define N_ 100
#define ABLK 35                 // ceil(A_/256)
#define HALF_N 50
#define GRID_A (ABLK * B_ * 2)  // 2240 per-anchor blocks (2 n-halves)
#define GB_G 4                  // GTs per branch-B block
#define GB_PB (N_ / GB_G)       // 25 groups per batch
#define GRID_B (B_ * GB_PB)     // 800
#define EPSF 1e-6f

// ws layout (all used regions fully overwritten every launch):
//   axyxy[A_] float4, partA[B_*A_*2] u64, aarea[A_] float,
//   garea[B_*N_] float, win[B_*N_] int

// ---------------------------------------------------------------------------
// K0 prologue: precompute anchor xyxy + areas and GT areas ONCE.
// an.z*0.5f is an exact product (exponent shift), so fma-contraction cannot
// change bits; remaining expressions are verbatim R4 -> bit-identical.
// ---------------------------------------------------------------------------
__global__ __launch_bounds__(256) void k_pre(
    const float* __restrict__ gt, const float* __restrict__ anchors,
    float4* __restrict__ axyxy, float* __restrict__ aarea,
    float* __restrict__ garea) {
  int i = blockIdx.x * 256 + threadIdx.x;
  if (i < A_) {
    float4 an = ((const float4*)anchors)[i];
    float ax0 = an.x - an.z * 0.5f, ay0 = an.y - an.w * 0.5f;
    float ax1 = an.x + an.z * 0.5f, ay1 = an.y + an.w * 0.5f;
    axyxy[i] = make_float4(ax0, ay0, ax1, ay1);
    aarea[i] = (ax1 - ax0) * (ay1 - ay0);
  } else if (i - A_ < B_ * N_) {
    int j = i - A_;
    const float* g = gt + (size_t)j * 4;
    float bx0 = g[0], by0 = g[1], bx1 = g[2], by1 = g[3];
    garea[j] = (bx1 - bx0) * (by1 - by0);
  }
}

// ---------------------------------------------------------------------------
// K1 merged scan — R4 key semantics VERBATIM, plus an EXACT division skip:
// when inter == 0, ref iou == +0 exactly, and all zero-iou candidates are
// represented by the init key (branch A: (0, 99-n0) >= (0,99-n) for all n in
// the half; branch B lane: (0, inv(tid)) >= (0, inv(a)) for all lane anchors).
// So `if (inter > 0) {...}` + those inits is bit-identical to the full scan.
// ~75% of GTs are inverted boxes (random corners) -> inter==0 for ALL lanes
// -> wave-uniform skip of the div/key body.
// ---------------------------------------------------------------------------
__global__ __launch_bounds__(256) void k_scan(
    const float* __restrict__ gt, const float4* __restrict__ axyxy,
    const float* __restrict__ aarea, const float* __restrict__ garea,
    unsigned long long* __restrict__ partA, int* __restrict__ win) {
  int tid = threadIdx.x;
  int bid = blockIdx.x;
  __shared__ unsigned long long sred[256];

  if (bid < GRID_A) {
    // ---- per-anchor argmax over one n-half: key = (iou, 99-n) ----
    int bx = bid % ABLK;
    int t = bid / ABLK;
    int b = t >> 1, half = t & 1;
    int a = bx * 256 + tid;
    bool valid = a < A_;
    int aa = valid ? a : (A_ - 1);

    float4 axy = axyxy[aa];
    float area_a = aarea[aa];
    const float4* g4 = (const float4*)(gt + (size_t)b * N_ * 4);  // uniform
    const float* ga = garea + b * N_;                             // uniform

    int n0 = half * HALF_N;
    // max zero-iou key of this half (n ascending -> 99-n decreasing)
    unsigned long long bestk = (unsigned long long)(unsigned)(N_ - 1 - n0);
#pragma unroll 2
    for (int i = 0; i < HALF_N; i++) {
      int n = n0 + i;
      float4 gb = g4[n];  // wave-uniform -> s_load
      float lx = fmaxf(axy.x, gb.x), ly = fmaxf(axy.y, gb.y);
      float rx = fminf(axy.z, gb.z), ry = fminf(axy.w, gb.w);
      float w = fmaxf(rx - lx, 0.0f), h = fmaxf(ry - ly, 0.0f);
      float inter = w * h;
      if (inter > 0.0f) {  // exact skip: iou==+0 covered by init key
        float area_b = ga[n];  // wave-uniform -> s_load
        float uni = area_a + area_b - inter;
        float iou = inter / fmaxf(uni, EPSF);
        unsigned long long key =
            (((unsigned long long)__float_as_uint(iou)) << 32) |
            (unsigned long long)(unsigned)(N_ - 1 - n);
        if (key > bestk) bestk = key;
      }
    }
    if (valid) partA[((size_t)b * A_ + a) * 2 + half] = bestk;
  } else {
    // ---- per-GT argmax over anchors, 4 GTs per block: key = (iou, inv a) --
    int bb = bid - GRID_A;
    int b = bb / GB_PB;
    int grp = bb - b * GB_PB;
    int nb = grp * GB_G;
    const float* g = gt + ((size_t)b * N_ + nb) * 4;  // block-uniform
    float gx0[GB_G], gy0[GB_G], gx1[GB_G], gy1[GB_G], gar[GB_G];
#pragma unroll
    for (int j = 0; j < GB_G; j++) {
      gx0[j] = g[j * 4 + 0];
      gy0[j] = g[j * 4 + 1];
      gx1[j] = g[j * 4 + 2];
      gy1[j] = g[j * 4 + 3];
      gar[j] = garea[b * N_ + nb + j];
    }
    unsigned long long bestk[GB_G];
#pragma unroll
    for (int j = 0; j < GB_G; j++)
      bestk[j] = (unsigned long long)(0xFFFFFFFFu - (unsigned)tid);

    for (int a = tid; a < A_; a += 256) {
      float4 axy = axyxy[a];
      float area_a = aarea[a];
#pragma unroll
      for (int j = 0; j < GB_G; j++) {
        float lx = fmaxf(axy.x, gx0[j]), ly = fmaxf(axy.y, gy0[j]);
        float rx = fminf(axy.z, gx1[j]), ry = fminf(axy.w, gy1[j]);
        float w = fmaxf(rx - lx, 0.0f), h = fmaxf(ry - ly, 0.0f);
        float inter = w * h;
        if (inter > 0.0f) {  // exact skip: covered by init key (0, inv(tid))
          float uni = area_a + gar[j] - inter;
          float iou = inter / fmaxf(uni, EPSF);
          unsigned long long key =
              (((unsigned long long)__float_as_uint(iou)) << 32) |
              (unsigned long long)(0xFFFFFFFFu - (unsigned)a);
          if (key > bestk[j]) bestk[j] = key;
        }
      }
    }
#pragma unroll
    for (int j = 0; j < GB_G; j++) {
      sred[tid] = bestk[j];
      __syncthreads();
      for (int s = 128; s > 0; s >>= 1) {
        if (tid < s) {
          unsigned long long o = sred[tid + s];
          if (o > sred[tid]) sred[tid] = o;
        }
        __syncthreads();
      }
      if (tid == 0)
        win[b * N_ + nb + j] =
            (int)(0xFFFFFFFFu - (unsigned)(sred[0] & 0xFFFFFFFFull));
      __syncthreads();
    }
  }
}

// ---------------------------------------------------------------------------
// K2: per (b, 256-anchor tile) — VERBATIM R4: merge half keys (tie -> higher
// 99-n = smaller n = first occurrence), apply LDS override table from win[]
// (atomicMax over n = last-write-wins index_put), encode, write outputs.
// ---------------------------------------------------------------------------
__global__ __launch_bounds__(256) void k_finalize(
    const float* __restrict__ gt, const int* __restrict__ labels,
    const float* __restrict__ anchors, const unsigned char* __restrict__ mask,
    const unsigned long long* __restrict__ partA, const int* __restrict__ win,
    float* __restrict__ out) {
  int b = blockIdx.y;
  int a0 = blockIdx.x * 256;
  int tid = threadIdx.x;
  int a = a0 + tid;

  __shared__ int s_ov[256];
  __shared__ int s_any;
  if (tid == 0) s_any = 0;
  s_ov[tid] = -1;
  __syncthreads();
  if (tid < N_) {
    int aw = win[b * N_ + tid];
    if (aw >= a0 && aw < a0 + 256) atomicMax(&s_ov[aw - a0], tid);
  }
  if (tid < 25) {
    unsigned v = ((const unsigned*)mask)[b * 25 + tid];
    if (v) atomicOr(&s_any, 1);
  }
  __syncthreads();
  if (a >= A_) return;

  size_t idx = (size_t)b * A_ + a;
  unsigned long long k0 = partA[idx * 2];
  unsigned long long k1 = partA[idx * 2 + 1];
  unsigned long long k = (k0 > k1) ? k0 : k1;
  float iou = __uint_as_float((unsigned)(k >> 32));
  int gi = (N_ - 1) - (int)(k & 0xFFFFFFFFull);

  int ov = s_ov[tid];
  bool pos;
  if (ov >= 0) {
    gi = ov;
    pos = true;  // scattered best_gt_iou = 2.0 > 0.5
  } else {
    pos = iou > 0.5f;
  }

  float4 an = ((const float4*)anchors)[a];
  const float* g = gt + (size_t)(b * N_ + gi) * 4;
  float gx = g[0], gy = g[1], gw = g[2], gh = g[3];

  float ex = (gx - an.x) / an.z;
  float ey = (gy - an.y) / an.w;
  float ew = logf((gw + EPSF) / (an.z + EPSF));
  float eh = logf((gh + EPSF) / (an.w + EPSF));
  int lab = pos ? labels[b * N_ + gi] : 0;

  if (!s_any) { ex = 0.0f; ey = 0.0f; ew = 0.0f; eh = 0.0f; lab = 0; }

  const long long BA = (long long)B_ * A_;
  ((float4*)out)[idx] = make_float4(ex, ey, ew, eh);  // encoded [B,A,4]
  out[4 * BA + idx] = (float)lab;                     // labels  [B,A]
  out[5 * BA + idx] = pos ? 1.0f : 0.0f;              // pos_mask[B,A]
}

extern "C" void kernel_launch(void* const* d_in, const int* in_sizes, int n_in,
                              void* d_out, int out_size, void* d_ws,
                              size_t ws_size, hipStream_t stream) {
  const float* gt = (const float*)d_in[0];
  const int* labels = (const int*)d_in[1];
  const unsigned char* mask = (const unsigned char*)d_in[2];
  const float* anchors = (const float*)d_in[3];
  float* out = (float*)d_out;

  // ws carve-up
  float4* axyxy = (float4*)d_ws;                              // A_ float4
  unsigned long long* partA = (unsigned long long*)(axyxy + A_);  // B*A*2 u64
  float* aarea = (float*)(partA + (size_t)B_ * A_ * 2);       // A_ float
  float* garea = aarea + A_;                                  // B_*N_ float
  int* win = (int*)(garea + B_ * N_);                         // B_*N_ int

  k_pre<<<(A_ + B_ * N_ + 255) / 256, 256, 0, stream>>>(gt, anchors, axyxy,
                                                        aarea, garea);
  k_scan<<<GRID_A + GRID_B, 256, 0, stream>>>(gt, axyxy, aarea, garea, partA,
                                              win);
  k_finalize<<<dim3(ABLK, B_), 256, 0, stream>>>(gt, labels, anchors, mask,
                                                 partA, win, out);
}

// Round 7
// 97.322 us; speedup vs baseline: 1.3199x; 1.0696x over previous
//
#include <hip/hip_runtime.h>

#define A_ 8732
#define B_ 32
#define N_ 100
#define ABLK 35            // ceil(A_/256)
#define GB_G 4             // GTs per scan block
#define GMAX 25            // max groups per batch (N_/GB_G)
#define EPSF 1e-6f

// ws layout (only regions written this launch are later read):
//   partial[B_*GMAX*A_] u64 (55.9 MB, only g<ceil(cnt/4) written+read)
//   axyxy[A_] float4, aarea[A_] float, cbox[B_*N_] float4,
//   carea[B_*N_] float, cn[B_*N_] int, cnt[B_] int, win[B_*N_] int

// ---------------------------------------------------------------------------
// K0: anchor xyxy/area precompute (blocks 0..ABLK-1) + one compaction block:
// valid GT = (x1>x0 && y1>y0) — inverted GTs have IoU == +0 vs EVERY anchor
// (rx <= gb.z < gb.x <= lx => w=0), so they are fully represented downstream
// by the zero-key inits. Compaction order is irrelevant: all consumers take
// max over order-free keys carrying the original n. win[] pre-init to 0
// (numpy argmax of an all-zero column = first anchor = 0).
// ---------------------------------------------------------------------------
__global__ __launch_bounds__(256) void k_pre(
    const float* __restrict__ gt, const float* __restrict__ anchors,
    float4* __restrict__ axyxy, float* __restrict__ aarea,
    float4* __restrict__ cbox, float* __restrict__ carea,
    int* __restrict__ cn, int* __restrict__ cnt, int* __restrict__ win) {
  int tid = threadIdx.x;
  if (blockIdx.x < ABLK) {
    int i = blockIdx.x * 256 + tid;
    if (i < A_) {
      float4 an = ((const float4*)anchors)[i];
      float ax0 = an.x - an.z * 0.5f, ay0 = an.y - an.w * 0.5f;
      float ax1 = an.x + an.z * 0.5f, ay1 = an.y + an.w * 0.5f;
      axyxy[i] = make_float4(ax0, ay0, ax1, ay1);
      aarea[i] = (ax1 - ax0) * (ay1 - ay0);
    }
    return;
  }
  // compaction block
  __shared__ int s_cnt[B_];
  if (tid < B_) s_cnt[tid] = 0;
  __syncthreads();
  for (int j = tid; j < B_ * N_; j += 256) {
    win[j] = 0;
    const float* g = gt + (size_t)j * 4;
    float bx0 = g[0], by0 = g[1], bx1 = g[2], by1 = g[3];
    if (bx1 > bx0 && by1 > by0) {
      int b = j / N_;
      int p = atomicAdd(&s_cnt[b], 1);
      cbox[b * N_ + p] = make_float4(bx0, by0, bx1, by1);
      carea[b * N_ + p] = (bx1 - bx0) * (by1 - by0);  // verbatim R6 expr
      cn[b * N_ + p] = j - b * N_;
    }
  }
  __syncthreads();
  if (tid < B_) cnt[tid] = s_cnt[tid];
}

// ---------------------------------------------------------------------------
// K1: block (b, g) scans all anchors for 4 compacted GTs, producing BOTH
// directions in one pass:
//  - per-anchor partial key (iou_bits<<32)|(99-n): written per (b,g,a);
//    init 0 (any inter>0 candidate beats it; finalize's (0,99) init
//    dominates all zero-iou candidates exactly).
//  - per-GT key (iou_bits<<32)|(inv a): per-lane init (0, inv tid) = lane's
//    first anchor, strict '>' = first-occurrence; LDS tree at the end.
// IoU expression verbatim R6 -> bit-identical. Dead j slots use an inverted
// dummy box (inter == 0, never contributes) and are never written back.
// ---------------------------------------------------------------------------
__global__ __launch_bounds__(256) void k_scan(
    const float4* __restrict__ axyxy, const float* __restrict__ aarea,
    const float4* __restrict__ cbox, const float* __restrict__ carea,
    const int* __restrict__ cn, const int* __restrict__ cnt,
    unsigned long long* __restrict__ partial, int* __restrict__ win) {
  int tid = threadIdx.x;
  int b = blockIdx.x / GMAX;
  int g = blockIdx.x % GMAX;
  int c = cnt[b];
  if (GB_G * g >= c) return;
  __shared__ unsigned long long sred[256];

  float gx0[GB_G], gy0[GB_G], gx1[GB_G], gy1[GB_G], gar[GB_G];
  int gn[GB_G];
  bool live[GB_G];
#pragma unroll
  for (int j = 0; j < GB_G; j++) {
    int p = GB_G * g + j;
    live[j] = p < c;
    int ps = live[j] ? p : 0;  // safe slot; value unused when dead
    float4 gb = cbox[b * N_ + ps];
    if (!live[j]) gb = make_float4(1.0f, 1.0f, 0.0f, 0.0f);  // inverted dummy
    gx0[j] = gb.x; gy0[j] = gb.y; gx1[j] = gb.z; gy1[j] = gb.w;
    gar[j] = carea[b * N_ + ps];
    gn[j] = live[j] ? cn[b * N_ + ps] : 0;
  }
  unsigned long long wkey[GB_G];
#pragma unroll
  for (int j = 0; j < GB_G; j++)
    wkey[j] = (unsigned long long)(0xFFFFFFFFu - (unsigned)tid);

  unsigned long long* prow = partial + ((size_t)b * GMAX + g) * A_;
  for (int a = tid; a < A_; a += 256) {
    float4 axy = axyxy[a];
    float area_a = aarea[a];
    unsigned long long pk = 0ull;
#pragma unroll
    for (int j = 0; j < GB_G; j++) {
      float lx = fmaxf(axy.x, gx0[j]), ly = fmaxf(axy.y, gy0[j]);
      float rx = fminf(axy.z, gx1[j]), ry = fminf(axy.w, gy1[j]);
      float w = fmaxf(rx - lx, 0.0f), h = fmaxf(ry - ly, 0.0f);
      float inter = w * h;
      if (inter > 0.0f) {  // exact skip: zero-iou covered by inits
        float uni = area_a + gar[j] - inter;
        float iou = inter / fmaxf(uni, EPSF);
        unsigned long long hi = ((unsigned long long)__float_as_uint(iou)) << 32;
        unsigned long long kA = hi | (unsigned long long)(unsigned)(N_ - 1 - gn[j]);
        if (kA > pk) pk = kA;
        unsigned long long kB = hi | (unsigned long long)(0xFFFFFFFFu - (unsigned)a);
        if (kB > wkey[j]) wkey[j] = kB;
      }
    }
    prow[a] = pk;
  }

#pragma unroll
  for (int j = 0; j < GB_G; j++) {
    sred[tid] = wkey[j];
    __syncthreads();
    for (int s = 128; s > 0; s >>= 1) {
      if (tid < s) {
        unsigned long long o = sred[tid + s];
        if (o > sred[tid]) sred[tid] = o;
      }
      __syncthreads();
    }
    if (tid == 0 && live[j])
      win[b * N_ + gn[j]] =
          (int)(0xFFFFFFFFu - (unsigned)(sred[0] & 0xFFFFFFFFull));
    __syncthreads();
  }
}

// ---------------------------------------------------------------------------
// K2: per (b, 256-anchor tile) — merge the batch's group partials starting
// from init (0,99) (decodes to gi=0 = numpy all-zero argmax; dominates every
// zero-iou candidate and 0ull partials), then verbatim R6 override/encode.
// ---------------------------------------------------------------------------
__global__ __launch_bounds__(256) void k_finalize(
    const float* __restrict__ gt, const int* __restrict__ labels,
    const float* __restrict__ anchors, const unsigned char* __restrict__ mask,
    const unsigned long long* __restrict__ partial, const int* __restrict__ cnt,
    const int* __restrict__ win, float* __restrict__ out) {
  int b = blockIdx.y;
  int a0 = blockIdx.x * 256;
  int tid = threadIdx.x;
  int a = a0 + tid;

  __shared__ int s_ov[256];
  __shared__ int s_any;
  if (tid == 0) s_any = 0;
  s_ov[tid] = -1;
  __syncthreads();
  if (tid < N_) {
    int aw = win[b * N_ + tid];
    if (aw >= a0 && aw < a0 + 256) atomicMax(&s_ov[aw - a0], tid);
  }
  if (tid < 25) {
    unsigned v = ((const unsigned*)mask)[b * 25 + tid];
    if (v) atomicOr(&s_any, 1);
  }
  __syncthreads();
  if (a >= A_) return;

  int G = (cnt[b] + GB_G - 1) / GB_G;  // block-uniform
  unsigned long long k = (unsigned long long)(unsigned)(N_ - 1);  // (0, n=0)
  const unsigned long long* prow = partial + (size_t)b * GMAX * A_ + a;
  for (int g = 0; g < G; g++) {
    unsigned long long t = prow[(size_t)g * A_];
    if (t > k) k = t;
  }
  float iou = __uint_as_float((unsigned)(k >> 32));
  int gi = (N_ - 1) - (int)(k & 0xFFFFFFFFull);

  int ov = s_ov[tid];
  bool pos;
  if (ov >= 0) {
    gi = ov;
    pos = true;  // scattered best_gt_iou = 2.0 > 0.5
  } else {
    pos = iou > 0.5f;
  }

  float4 an = ((const float4*)anchors)[a];
  const float* g = gt + (size_t)(b * N_ + gi) * 4;
  float gx = g[0], gy = g[1], gw = g[2], gh = g[3];

  float ex = (gx - an.x) / an.z;
  float ey = (gy - an.y) / an.w;
  float ew = logf((gw + EPSF) / (an.z + EPSF));
  float eh = logf((gh + EPSF) / (an.w + EPSF));
  int lab = pos ? labels[b * N_ + gi] : 0;

  if (!s_any) { ex = 0.0f; ey = 0.0f; ew = 0.0f; eh = 0.0f; lab = 0; }

  const long long BA = (long long)B_ * A_;
  ((float4*)out)[(size_t)b * A_ + a] = make_float4(ex, ey, ew, eh);
  out[4 * BA + (size_t)b * A_ + a] = (float)lab;
  out[5 * BA + (size_t)b * A_ + a] = pos ? 1.0f : 0.0f;
}

extern "C" void kernel_launch(void* const* d_in, const int* in_sizes, int n_in,
                              void* d_out, int out_size, void* d_ws,
                              size_t ws_size, hipStream_t stream) {
  const float* gt = (const float*)d_in[0];
  const int* labels = (const int*)d_in[1];
  const unsigned char* mask = (const unsigned char*)d_in[2];
  const float* anchors = (const float*)d_in[3];
  float* out = (float*)d_out;

  // ws carve-up (16B-aligned head first)
  unsigned long long* partial = (unsigned long long*)d_ws;  // B*GMAX*A u64
  float4* axyxy = (float4*)(partial + (size_t)B_ * GMAX * A_);  // A_ float4
  float4* cbox = axyxy + A_;                                // B*N float4
  float* aarea = (float*)(cbox + B_ * N_);                  // A_ float
  float* carea = aarea + A_;                                // B*N float
  int* cn = (int*)(carea + B_ * N_);                        // B*N int
  int* cnt = cn + B_ * N_;                                  // B_ int
  int* win = cnt + B_;                                      // B*N int

  k_pre<<<ABLK + 1, 256, 0, stream>>>(gt, anchors, axyxy, aarea, cbox, carea,
                                      cn, cnt, win);
  k_scan<<<B_ * GMAX, 256, 0, stream>>>(axyxy, aarea, cbox, carea, cn, cnt,
                                        partial, win);
  k_finalize<<<dim3(ABLK, B_), 256, 0, stream>>>(gt, labels, anchors, mask,
                                                 partial, cnt, win, out);
}

// Round 8
// 87.356 us; speedup vs baseline: 1.4705x; 1.1141x over previous
//
#include <hip/hip_runtime.h>

#define A_ 8732
#define B_ 32
#define N_ 100
#define ABLK 35            // ceil(A_/256)
#define GB_G 4             // GTs per scan block
#define GMAX 25            // max groups per batch (N_/GB_G)
#define SPLIT 8            // anchor-axis splits per group
#define SLEN 1092          // ceil(A_/SPLIT); last split = 1088 (>256, so every
                           // lane owns >=1 anchor per split)
#define EPSF 1e-6f

// ws layout (only regions written this launch are later read):
//   partial[B_*GMAX*A_] u64 (55.9 MB; only planes g<ceil(cnt/4) written+read)
//   wsplit[B_*SPLIT*N_] u64 (205 KB; only valid-n slots written+read)
//   cbox[B_*N_] float4, carea[B_*N_] float, cn[B_*N_] int, cnt[B_] int

// ---------------------------------------------------------------------------
// K0: single-block compaction of valid GTs (x1>x0 && y1>y0). Inverted GTs
// have IoU == +0 vs EVERY anchor (rx <= gb.z < gb.x <= lx => w=0) and are
// handled exactly by the zero-key inits downstream. Compaction order is
// irrelevant: all consumers take max over order-free keys carrying original n.
// ---------------------------------------------------------------------------
__global__ __launch_bounds__(256) void k_pre(
    const float* __restrict__ gt, float4* __restrict__ cbox,
    float* __restrict__ carea, int* __restrict__ cn, int* __restrict__ cnt) {
  __shared__ int s_cnt[B_];
  int tid = threadIdx.x;
  if (tid < B_) s_cnt[tid] = 0;
  __syncthreads();
  for (int j = tid; j < B_ * N_; j += 256) {
    float4 gb = ((const float4*)gt)[j];
    if (gb.z > gb.x && gb.w > gb.y) {
      int b = j / N_;
      int p = atomicAdd(&s_cnt[b], 1);
      cbox[b * N_ + p] = gb;
      carea[b * N_ + p] = (gb.z - gb.x) * (gb.w - gb.y);  // verbatim expr
      cn[b * N_ + p] = j - b * N_;
    }
  }
  __syncthreads();
  if (tid < B_) cnt[tid] = s_cnt[tid];
}

// ---------------------------------------------------------------------------
// K1: block (b, g, s) scans anchors [s*SLEN, min(A_, (s+1)*SLEN)) for 4
// compacted GTs; BOTH directions in one pass. ~1792 live blocks => ~28
// waves/CU (R7 had 224 blocks = 1 wave/SIMD, fully latency-exposed).
//  - per-anchor partial key (iou<<32)|(99-n) -> prow[a] (one writer per a).
//  - per-GT key (iou<<32)|(inv a); per-lane init (0, inv(first lane anchor));
//    LDS tree -> wsplit[b][s][n]. Cross-split max in finalize keeps global
//    first-occurrence (inv strictly decreasing in a).
// Anchor xyxy/area inline: *0.5f is exact (exponent shift) so contraction
// cannot change bits; expressions verbatim from the R7-passing kernel.
// ---------------------------------------------------------------------------
__global__ __launch_bounds__(256) void k_scan(
    const float* __restrict__ anchors, const float4* __restrict__ cbox,
    const float* __restrict__ carea, const int* __restrict__ cn,
    const int* __restrict__ cnt, unsigned long long* __restrict__ partial,
    unsigned long long* __restrict__ wsplit) {
  int tid = threadIdx.x;
  int bid = blockIdx.x;
  int s = bid % SPLIT;
  int t = bid / SPLIT;  // b*GMAX + g
  int g = t % GMAX;
  int b = t / GMAX;
  int c = cnt[b];
  if (GB_G * g >= c) return;
  __shared__ unsigned long long sred[256];

  float gx0[GB_G], gy0[GB_G], gx1[GB_G], gy1[GB_G], gar[GB_G];
  int gn[GB_G];
  bool live[GB_G];
#pragma unroll
  for (int j = 0; j < GB_G; j++) {
    int p = GB_G * g + j;
    live[j] = p < c;
    int ps = live[j] ? p : 0;
    float4 gb = cbox[b * N_ + ps];
    if (!live[j]) gb = make_float4(1.0f, 1.0f, 0.0f, 0.0f);  // inverted dummy
    gx0[j] = gb.x; gy0[j] = gb.y; gx1[j] = gb.z; gy1[j] = gb.w;
    gar[j] = carea[b * N_ + ps];
    gn[j] = live[j] ? cn[b * N_ + ps] : 0;
  }

  int s0 = s * SLEN;
  int send = (s0 + SLEN < A_) ? (s0 + SLEN) : A_;

  unsigned long long wkey[GB_G];
#pragma unroll
  for (int j = 0; j < GB_G; j++)
    wkey[j] = (unsigned long long)(0xFFFFFFFFu - (unsigned)(s0 + tid));

  unsigned long long* prow = partial + ((size_t)b * GMAX + g) * A_;
  for (int a = s0 + tid; a < send; a += 256) {
    float4 an = ((const float4*)anchors)[a];
    float ax0 = an.x - an.z * 0.5f, ay0 = an.y - an.w * 0.5f;
    float ax1 = an.x + an.z * 0.5f, ay1 = an.y + an.w * 0.5f;
    float area_a = (ax1 - ax0) * (ay1 - ay0);
    unsigned long long pk = 0ull;
#pragma unroll
    for (int j = 0; j < GB_G; j++) {
      float lx = fmaxf(ax0, gx0[j]), ly = fmaxf(ay0, gy0[j]);
      float rx = fminf(ax1, gx1[j]), ry = fminf(ay1, gy1[j]);
      float w = fmaxf(rx - lx, 0.0f), h = fmaxf(ry - ly, 0.0f);
      float inter = w * h;
      if (inter > 0.0f) {  // exact skip: zero-iou covered by inits
        float uni = area_a + gar[j] - inter;
        float iou = inter / fmaxf(uni, EPSF);
        unsigned long long hi = ((unsigned long long)__float_as_uint(iou)) << 32;
        unsigned long long kA = hi | (unsigned long long)(unsigned)(N_ - 1 - gn[j]);
        if (kA > pk) pk = kA;
        unsigned long long kB = hi | (unsigned long long)(0xFFFFFFFFu - (unsigned)a);
        if (kB > wkey[j]) wkey[j] = kB;
      }
    }
    prow[a] = pk;
  }

#pragma unroll
  for (int j = 0; j < GB_G; j++) {
    sred[tid] = wkey[j];
    __syncthreads();
    for (int r = 128; r > 0; r >>= 1) {
      if (tid < r) {
        unsigned long long o = sred[tid + r];
        if (o > sred[tid]) sred[tid] = o;
      }
      __syncthreads();
    }
    if (tid == 0 && live[j])
      wsplit[((size_t)b * SPLIT + s) * N_ + gn[j]] = sred[0];
    __syncthreads();
  }
}

// ---------------------------------------------------------------------------
// K2: per (b, 256-anchor tile). Per-n winner: inverted GT (recomputed with
// the SAME predicate as compaction) -> aw=0 (numpy zero-column argmax);
// valid -> max over 8 split keys. Override table via LDS atomicMax over n
// (= last-write-wins index_put). Per-anchor merge over G planes from init
// (0,99) (decodes gi=0; dominates all zero-iou candidates and 0ull partials).
// Encode expressions verbatim R7.
// ---------------------------------------------------------------------------
__global__ __launch_bounds__(256) void k_finalize(
    const float* __restrict__ gt, const int* __restrict__ labels,
    const float* __restrict__ anchors, const unsigned char* __restrict__ mask,
    const unsigned long long* __restrict__ partial,
    const unsigned long long* __restrict__ wsplit,
    const int* __restrict__ cnt, float* __restrict__ out) {
  int b = blockIdx.y;
  int a0 = blockIdx.x * 256;
  int tid = threadIdx.x;
  int a = a0 + tid;

  __shared__ int s_ov[256];
  __shared__ int s_any;
  if (tid == 0) s_any = 0;
  s_ov[tid] = -1;
  __syncthreads();
  if (tid < N_) {
    float4 gb = ((const float4*)gt)[b * N_ + tid];
    int aw = 0;  // inverted GT: all-zero column -> argmax anchor 0
    if (gb.z > gb.x && gb.w > gb.y) {
      const unsigned long long* wp = wsplit + (size_t)b * SPLIT * N_ + tid;
      unsigned long long k = wp[0];
#pragma unroll
      for (int s2 = 1; s2 < SPLIT; s2++) {
        unsigned long long tk = wp[(size_t)s2 * N_];
        if (tk > k) k = tk;
      }
      aw = (int)(0xFFFFFFFFu - (unsigned)(k & 0xFFFFFFFFull));
    }
    if (aw >= a0 && aw < a0 + 256) atomicMax(&s_ov[aw - a0], tid);
  }
  if (tid < 25) {
    unsigned v = ((const unsigned*)mask)[b * 25 + tid];
    if (v) atomicOr(&s_any, 1);
  }
  __syncthreads();
  if (a >= A_) return;

  int G = (cnt[b] + GB_G - 1) / GB_G;  // block-uniform
  unsigned long long k = (unsigned long long)(unsigned)(N_ - 1);  // (0, n=0)
  const unsigned long long* prow = partial + (size_t)b * GMAX * A_ + a;
  for (int g2 = 0; g2 < G; g2++) {
    unsigned long long t2 = prow[(size_t)g2 * A_];
    if (t2 > k) k = t2;
  }
  float iou = __uint_as_float((unsigned)(k >> 32));
  int gi = (N_ - 1) - (int)(k & 0xFFFFFFFFull);

  int ov = s_ov[tid];
  bool pos;
  if (ov >= 0) {
    gi = ov;
    pos = true;  // scattered best_gt_iou = 2.0 > 0.5
  } else {
    pos = iou > 0.5f;
  }

  float4 an = ((const float4*)anchors)[a];
  const float* g = gt + (size_t)(b * N_ + gi) * 4;
  float gx = g[0], gy = g[1], gw = g[2], gh = g[3];

  float ex = (gx - an.x) / an.z;
  float ey = (gy - an.y) / an.w;
  float ew = logf((gw + EPSF) / (an.z + EPSF));
  float eh = logf((gh + EPSF) / (an.w + EPSF));
  int lab = pos ? labels[b * N_ + gi] : 0;

  if (!s_any) { ex = 0.0f; ey = 0.0f; ew = 0.0f; eh = 0.0f; lab = 0; }

  const long long BA = (long long)B_ * A_;
  ((float4*)out)[(size_t)b * A_ + a] = make_float4(ex, ey, ew, eh);
  out[4 * BA + (size_t)b * A_ + a] = (float)lab;
  out[5 * BA + (size_t)b * A_ + a] = pos ? 1.0f : 0.0f;
}

extern "C" void kernel_launch(void* const* d_in, const int* in_sizes, int n_in,
                              void* d_out, int out_size, void* d_ws,
                              size_t ws_size, hipStream_t stream) {
  const float* gt = (const float*)d_in[0];
  const int* labels = (const int*)d_in[1];
  const unsigned char* mask = (const unsigned char*)d_in[2];
  const float* anchors = (const float*)d_in[3];
  float* out = (float*)d_out;

  // ws carve-up (all 16B-aligned: sizes are multiples of 16)
  unsigned long long* partial = (unsigned long long*)d_ws;       // B*GMAX*A
  unsigned long long* wsplit = partial + (size_t)B_ * GMAX * A_; // B*SPLIT*N
  float4* cbox = (float4*)(wsplit + (size_t)B_ * SPLIT * N_);    // B*N
  float* carea = (float*)(cbox + B_ * N_);                       // B*N
  int* cn = (int*)(carea + B_ * N_);                             // B*N
  int* cnt = cn + B_ * N_;                                       // B_

  k_pre<<<1, 256, 0, stream>>>(gt, cbox, carea, cn, cnt);
  k_scan<<<B_ * GMAX * SPLIT, 256, 0, stream>>>(anchors, cbox, carea, cn, cnt,
                                                partial, wsplit);
  k_finalize<<<dim3(ABLK, B_), 256, 0, stream>>>(gt, labels, anchors, mask,
                                                 partial, wsplit, cnt, out);
}

// Round 9
// 82.934 us; speedup vs baseline: 1.5489x; 1.0533x over previous
//
#include <hip/hip_runtime.h>

#define A_ 8732
#define B_ 32
#define N_ 100
#define ABLK 35            // ceil(A_/256)
#define GB_G 4             // GTs per scan block
#define GMAX 25            // max groups per batch (N_/GB_G)
#define SPLIT 8            // anchor-axis splits per group
#define SLEN 1092          // ceil(A_/SPLIT); last split = 1088 (>=256)
#define EPSF 1e-6f

// ws layout (only regions written this launch are later read):
//   partial[B_*GMAX*A_] u64 (only planes g<ceil(c/4) written+read)
//   wsplit[B_*SPLIT*N_] u64 (only valid-n slots written+read)

// Deterministic in-block compaction of valid GTs (x1>x0 && y1>y0), rank =
// ascending original n — identical in every block of a batch, which the
// split-coverage argument requires. Inverted GTs have IoU == +0 vs EVERY
// anchor (rx <= x1 < x0 <= lx => w=0) and are handled exactly by the
// zero-key inits downstream.

// ---------------------------------------------------------------------------
// K1: block (b, g, s) scans anchors [s*SLEN, min(A_,(s+1)*SLEN)) for the 4
// GTs of compacted group g; BOTH directions in one pass (verbatim R8 math):
//  - per-anchor partial key (iou<<32)|(99-n) -> prow[a] (one writer per a).
//  - per-GT key (iou<<32)|(inv a); per-lane init (0, inv(first lane anchor));
//    in-wave shfl_xor max (6 rounds, no barriers) + 4-entry cross-wave LDS
//    merge -> wsplit[b][s][n]. Cross-split max in finalize keeps global
//    first-occurrence (inv strictly decreasing in a).
// ---------------------------------------------------------------------------
__global__ __launch_bounds__(256) void k_scan(
    const float* __restrict__ gt, const float* __restrict__ anchors,
    unsigned long long* __restrict__ partial,
    unsigned long long* __restrict__ wsplit) {
  int tid = threadIdx.x;
  int lane = tid & 63, wid = tid >> 6;
  int bid = blockIdx.x;
  int s = bid % SPLIT;
  int t = bid / SPLIT;
  int g = t % GMAX;
  int b = t / GMAX;

  __shared__ unsigned long long s_bal[2];
  __shared__ int s_slot[N_];
  __shared__ unsigned long long s_w[4][GB_G];

  // ---- deterministic compaction ----
  bool v = false;
  float4 myg;
  if (tid < N_) {
    myg = ((const float4*)gt)[b * N_ + tid];
    v = (myg.z > myg.x && myg.w > myg.y);
  }
  unsigned long long bal = __ballot(v);
  if (lane == 0 && wid < 2) s_bal[wid] = bal;
  __syncthreads();
  int c0 = __popcll(s_bal[0]);
  int c = c0 + __popcll(s_bal[1]);  // waves 2,3: tid>=128 -> v=false
  if (v) {
    int rank = __popcll(bal & ((1ull << lane) - 1)) + (wid ? c0 : 0);
    s_slot[rank] = tid;
  }
  __syncthreads();
  if (GB_G * g >= c) return;

  // ---- load this group's 4 GTs (area expr verbatim) ----
  float gx0[GB_G], gy0[GB_G], gx1[GB_G], gy1[GB_G], gar[GB_G];
  int gn[GB_G];
  bool live[GB_G];
#pragma unroll
  for (int j = 0; j < GB_G; j++) {
    int p = GB_G * g + j;
    live[j] = p < c;
    int nj = live[j] ? s_slot[p] : 0;
    gn[j] = nj;
    float4 gb = ((const float4*)gt)[b * N_ + nj];
    if (!live[j]) gb = make_float4(1.0f, 1.0f, 0.0f, 0.0f);  // inverted dummy
    gx0[j] = gb.x; gy0[j] = gb.y; gx1[j] = gb.z; gy1[j] = gb.w;
    gar[j] = (gb.z - gb.x) * (gb.w - gb.y);
  }

  int s0 = s * SLEN;
  int send = (s0 + SLEN < A_) ? (s0 + SLEN) : A_;

  unsigned long long wkey[GB_G];
#pragma unroll
  for (int j = 0; j < GB_G; j++)
    wkey[j] = (unsigned long long)(0xFFFFFFFFu - (unsigned)(s0 + tid));

  unsigned long long* prow = partial + ((size_t)b * GMAX + g) * A_;
  for (int a = s0 + tid; a < send; a += 256) {
    float4 an = ((const float4*)anchors)[a];
    float ax0 = an.x - an.z * 0.5f, ay0 = an.y - an.w * 0.5f;
    float ax1 = an.x + an.z * 0.5f, ay1 = an.y + an.w * 0.5f;
    float area_a = (ax1 - ax0) * (ay1 - ay0);
    unsigned long long pk = 0ull;
#pragma unroll
    for (int j = 0; j < GB_G; j++) {
      float lx = fmaxf(ax0, gx0[j]), ly = fmaxf(ay0, gy0[j]);
      float rx = fminf(ax1, gx1[j]), ry = fminf(ay1, gy1[j]);
      float w = fmaxf(rx - lx, 0.0f), h = fmaxf(ry - ly, 0.0f);
      float inter = w * h;
      if (inter > 0.0f) {  // exact skip: zero-iou covered by inits
        float uni = area_a + gar[j] - inter;
        float iou = inter / fmaxf(uni, EPSF);
        unsigned long long hi = ((unsigned long long)__float_as_uint(iou)) << 32;
        unsigned long long kA = hi | (unsigned long long)(unsigned)(N_ - 1 - gn[j]);
        if (kA > pk) pk = kA;
        unsigned long long kB = hi | (unsigned long long)(0xFFFFFFFFu - (unsigned)a);
        if (kB > wkey[j]) wkey[j] = kB;
      }
    }
    prow[a] = pk;
  }

  // ---- per-GT reduction: in-wave shfl_xor max, then cross-wave merge ----
#pragma unroll
  for (int j = 0; j < GB_G; j++) {
    unsigned long long k = wkey[j];
#pragma unroll
    for (int off = 32; off; off >>= 1) {
      unsigned long long o = __shfl_xor(k, off, 64);
      if (o > k) k = o;
    }
    if (lane == 0) s_w[wid][j] = k;
  }
  __syncthreads();
  if (tid < GB_G) {
    int j = tid;
    if (GB_G * g + j < c) {
      unsigned long long k = s_w[0][j];
#pragma unroll
      for (int w2 = 1; w2 < 4; w2++)
        if (s_w[w2][j] > k) k = s_w[w2][j];
      wsplit[((size_t)b * SPLIT + s) * N_ + s_slot[GB_G * g + j]] = k;
    }
  }
}

// ---------------------------------------------------------------------------
// K2: per (b, 256-anchor tile) — verbatim R8, with c recomputed by the same
// deterministic ballot (G = ceil(c/4) bounds the plane merge). Per-n winner:
// inverted GT -> aw=0 (numpy zero-column argmax); valid -> max over 8 split
// keys. Override via LDS atomicMax over n (= last-write-wins index_put).
// Per-anchor merge from init (0,99) (decodes gi=0; dominates all zero-iou
// candidates and 0ull partials). Encode expressions verbatim.
// ---------------------------------------------------------------------------
__global__ __launch_bounds__(256) void k_finalize(
    const float* __restrict__ gt, const int* __restrict__ labels,
    const float* __restrict__ anchors, const unsigned char* __restrict__ mask,
    const unsigned long long* __restrict__ partial,
    const unsigned long long* __restrict__ wsplit, float* __restrict__ out) {
  int b = blockIdx.y;
  int a0 = blockIdx.x * 256;
  int tid = threadIdx.x;
  int lane = tid & 63, wid = tid >> 6;
  int a = a0 + tid;

  __shared__ int s_ov[256];
  __shared__ int s_any;
  __shared__ unsigned long long s_bal[2];

  bool v = false;
  if (tid < N_) {
    float4 gb = ((const float4*)gt)[b * N_ + tid];
    v = (gb.z > gb.x && gb.w > gb.y);
  }
  unsigned long long bal = __ballot(v);
  if (lane == 0 && wid < 2) s_bal[wid] = bal;
  if (tid == 0) s_any = 0;
  s_ov[tid] = -1;
  __syncthreads();
  int c = __popcll(s_bal[0]) + __popcll(s_bal[1]);

  if (tid < N_) {
    int aw = 0;  // inverted GT: all-zero column -> argmax anchor 0
    if (v) {
      const unsigned long long* wp = wsplit + (size_t)b * SPLIT * N_ + tid;
      unsigned long long k = wp[0];
#pragma unroll
      for (int s2 = 1; s2 < SPLIT; s2++) {
        unsigned long long tk = wp[(size_t)s2 * N_];
        if (tk > k) k = tk;
      }
      aw = (int)(0xFFFFFFFFu - (unsigned)(k & 0xFFFFFFFFull));
    }
    if (aw >= a0 && aw < a0 + 256) atomicMax(&s_ov[aw - a0], tid);
  }
  if (tid < 25) {
    unsigned mv = ((const unsigned*)mask)[b * 25 + tid];
    if (mv) atomicOr(&s_any, 1);
  }
  __syncthreads();
  if (a >= A_) return;

  int G = (c + GB_G - 1) / GB_G;  // block-uniform
  unsigned long long k = (unsigned long long)(unsigned)(N_ - 1);  // (0, n=0)
  const unsigned long long* prow = partial + (size_t)b * GMAX * A_ + a;
  for (int g2 = 0; g2 < G; g2++) {
    unsigned long long t2 = prow[(size_t)g2 * A_];
    if (t2 > k) k = t2;
  }
  float iou = __uint_as_float((unsigned)(k >> 32));
  int gi = (N_ - 1) - (int)(k & 0xFFFFFFFFull);

  int ov = s_ov[tid];
  bool pos;
  if (ov >= 0) {
    gi = ov;
    pos = true;  // scattered best_gt_iou = 2.0 > 0.5
  } else {
    pos = iou > 0.5f;
  }

  float4 an = ((const float4*)anchors)[a];
  const float* g = gt + (size_t)(b * N_ + gi) * 4;
  float gx = g[0], gy = g[1], gw = g[2], gh = g[3];

  float ex = (gx - an.x) / an.z;
  float ey = (gy - an.y) / an.w;
  float ew = logf((gw + EPSF) / (an.z + EPSF));
  float eh = logf((gh + EPSF) / (an.w + EPSF));
  int lab = pos ? labels[b * N_ + gi] : 0;

  if (!s_any) { ex = 0.0f; ey = 0.0f; ew = 0.0f; eh = 0.0f; lab = 0; }

  const long long BA = (long long)B_ * A_;
  ((float4*)out)[(size_t)b * A_ + a] = make_float4(ex, ey, ew, eh);
  out[4 * BA + (size_t)b * A_ + a] = (float)lab;
  out[5 * BA + (size_t)b * A_ + a] = pos ? 1.0f : 0.0f;
}

extern "C" void kernel_launch(void* const* d_in, const int* in_sizes, int n_in,
                              void* d_out, int out_size, void* d_ws,
                              size_t ws_size, hipStream_t stream) {
  const float* gt = (const float*)d_in[0];
  const int* labels = (const int*)d_in[1];
  const unsigned char* mask = (const unsigned char*)d_in[2];
  const float* anchors = (const float*)d_in[3];
  float* out = (float*)d_out;

  unsigned long long* partial = (unsigned long long*)d_ws;        // B*GMAX*A
  unsigned long long* wsplit = partial + (size_t)B_ * GMAX * A_;  // B*SPLIT*N

  k_scan<<<B_ * GMAX * SPLIT, 256, 0, stream>>>(gt, anchors, partial, wsplit);
  k_finalize<<<dim3(ABLK, B_), 256, 0, stream>>>(gt, labels, anchors, mask,
                                                 partial, wsplit, out);
}